// Round 3
// baseline (650.308 us; speedup 1.0000x reference)
//
#include <hip/hip_runtime.h>
#include <hip/hip_bf16.h>
#include <stdint.h>

#define T_TOK 4096
#define H_DIM 2048
#define I_DIM 1024
#define E_NUM 8
#define NPAIR 8192           // T_TOK * K_SEL
#define BM 256
#define BK 64
#define MAX_TILES 40         // worst case sum(ceil(M_e/256)) = 39
#define CAP (MAX_TILES * BM) // 10240 padded pair slots
#define NG1 (MAX_TILES * 8)
#define NG2 (MAX_TILES * 8)
#define NCB (T_TOK / 16)
#define NITEMS (NG1 + NG2 + NCB)

typedef short s16x8 __attribute__((ext_vector_type(8)));
typedef __bf16 bf16x8 __attribute__((ext_vector_type(8)));
typedef float f32x4 __attribute__((ext_vector_type(4)));

using gas1_t = const __attribute__((address_space(1))) void*;
using las3_t = __attribute__((address_space(3))) void*;

__device__ __forceinline__ void async_lds16(const void* g, void* l) {
  __builtin_amdgcn_global_load_lds((gas1_t)(uintptr_t)g,
                                   (las3_t)(uint32_t)(uintptr_t)l, 16, 0, 0);
}

__device__ __forceinline__ unsigned short f2bf(float f) {
  union { float f; unsigned int u; } v; v.f = f;
  unsigned int r = v.u + 0x7FFF + ((v.u >> 16) & 1); // RNE
  return (unsigned short)(r >> 16);
}

__device__ __forceinline__ f32x4 mfma_bf16(s16x8 a, s16x8 b, f32x4 c) {
  return __builtin_amdgcn_mfma_f32_16x16x32_bf16(
      __builtin_bit_cast(bf16x8, a), __builtin_bit_cast(bf16x8, b), c, 0, 0, 0);
}

__device__ __forceinline__ void atom_add_f32(float* p, float v) {
#if defined(__gfx950__) || defined(__gfx942__) || defined(__gfx90a__)
  unsafeAtomicAdd(p, v);
#else
  atomicAdd(p, v);
#endif
}

// ---------------------------------------------------------------- routing ---
// ctrl[0]=qhead, ctrl[1]=g2done, ctrl[2+mt]=done1[mt]
__global__ void routing_kernel(const int* __restrict__ sel,
                               const float* __restrict__ rw,
                               int* __restrict__ pair_token,
                               float* __restrict__ pair_weight,
                               int* __restrict__ inv,
                               int* __restrict__ tile_expert,
                               int* __restrict__ tile_pos,
                               int* __restrict__ ctrl) {
  __shared__ int cnt[E_NUM], off[E_NUM], fil[E_NUM];
  const int tid = threadIdx.x;
  if (tid < E_NUM) { cnt[tid] = 0; fil[tid] = 0; }
  for (int i = tid; i < 2 + MAX_TILES; i += blockDim.x) ctrl[i] = 0;
  __syncthreads();
  for (int p = tid; p < NPAIR; p += blockDim.x) atomicAdd(&cnt[sel[p]], 1);
  for (int q = tid; q < CAP; q += blockDim.x) { pair_token[q] = 0; pair_weight[q] = 0.f; }
  __syncthreads();
  if (tid == 0) {
    int run = 0, idx = 0;
    for (int e = 0; e < E_NUM; ++e) {
      off[e] = run;
      int nt = (cnt[e] + BM - 1) / BM;
      for (int t = 0; t < nt; ++t) { tile_expert[idx] = e; tile_pos[idx] = run + t * BM; ++idx; }
      run += nt * BM;
    }
    for (; idx < MAX_TILES; ++idx) tile_expert[idx] = -1;
  }
  __syncthreads();
  for (int p = tid; p < NPAIR; p += blockDim.x) {
    const int e = sel[p];
    const int pos = off[e] + atomicAdd(&fil[e], 1);
    pair_token[pos] = p >> 1;   // K_SEL == 2
    pair_weight[pos] = rw[p];
    inv[p] = pos;
  }
}

// ----------------------------------------------- prep: zero out + cvt x -----
__global__ void prep_kernel(const float4* __restrict__ x, ushort4* __restrict__ xb,
                            float4* __restrict__ out, int n4) {
  int i = blockIdx.x * blockDim.x + threadIdx.x;
  const int s = gridDim.x * blockDim.x;
  const float4 z = make_float4(0.f, 0.f, 0.f, 0.f);
  for (; i < n4; i += s) {
    out[i] = z;
    const float4 v = x[i];
    ushort4 r;
    r.x = f2bf(v.x); r.y = f2bf(v.y); r.z = f2bf(v.z); r.w = f2bf(v.w);
    xb[i] = r;
  }
}

// ---------------------------------------- transpose+cvt all three weights ---
__global__ void transpose_all(const float* __restrict__ Wg,
                              const float* __restrict__ Wu,
                              const float* __restrict__ Wd,
                              unsigned short* __restrict__ WguT,
                              unsigned short* __restrict__ WdT) {
  const int z = blockIdx.y;     // 0..23
  const int e = z & 7;
  const int which = z >> 3;
  const int tile = blockIdx.x;  // 512 tiles of 64x64
  int r0, c0, C;
  const float* src;
  if (which < 2) { C = 1024; r0 = (tile >> 4) * 64; c0 = (tile & 15) * 64;
                   src = (which ? Wu : Wg) + (size_t)e * H_DIM * I_DIM; }
  else           { C = 2048; r0 = (tile >> 5) * 64; c0 = (tile & 31) * 64;
                   src = Wd + (size_t)e * H_DIM * I_DIM; }

  __shared__ unsigned short Tl[64][72];
  const int k = threadIdx.x;        // 256 threads
  const int rr = k >> 2;
  const int cb = (k & 3) * 16;
  const float4* s4 = (const float4*)(src + (size_t)(r0 + rr) * C + c0 + cb);
  unsigned short* dstl = &Tl[rr][cb];
#pragma unroll
  for (int q = 0; q < 4; ++q) {
    const float4 v = s4[q];
    dstl[q * 4 + 0] = f2bf(v.x); dstl[q * 4 + 1] = f2bf(v.y);
    dstl[q * 4 + 2] = f2bf(v.z); dstl[q * 4 + 3] = f2bf(v.w);
  }
  __syncthreads();
  const int oc = k >> 2, rb = (k & 3) * 16;
  union { unsigned short us[16]; uint4 u4[2]; } pk;
#pragma unroll
  for (int i = 0; i < 16; ++i) pk.us[i] = Tl[rb + i][oc];
  const int gc = c0 + oc;
  unsigned short* dst;
  if (which < 2) {
    const int orow = (gc >> 4) * 32 + (gc & 15) + which * 16;
    dst = WguT + ((size_t)e * 2048 + orow) * 2048 + r0 + rb;
  } else {
    dst = WdT + ((size_t)e * 2048 + gc) * 1024 + r0 + rb;
  }
  uint4* d4 = (uint4*)dst;
  d4[0] = pk.u4[0]; d4[1] = pk.u4[1];
}

// ----------------------------------------------------- 8-phase 256^2 GEMM ---
__device__ __forceinline__ void stage2(unsigned short* dst,
                                       const unsigned short* s0,
                                       const unsigned short* s1) {
  async_lds16(s0, dst);
  async_lds16(s1, dst + 4096);
}

template<int QM>
__device__ __forceinline__ void lds_a(const unsigned short* shA, int slotA,
                                      int wm, int fr, int fq, s16x8 aF[4][2]) {
#pragma unroll
  for (int g = 0; g < 4; ++g)
#pragma unroll
    for (int kk = 0; kk < 2; ++kk) {
      const int ra = QM * 64 + g * 16 + fr;
      aF[g][kk] = *(const s16x8*)&shA[slotA * 8192 + ra * 64 +
                                      (((kk * 4 + fq) ^ (ra & 7)) * 8)];
    }
}

template<int QN>
__device__ __forceinline__ void lds_b(const unsigned short* shB, int slotB,
                                      int wn64, int fr, int fq, s16x8 bF[2][2][2]) {
#pragma unroll
  for (int g = 0; g < 2; ++g)
#pragma unroll
    for (int kk = 0; kk < 2; ++kk) {
      const int rb = wn64 + QN * 32 + g * 16 + fr;
      bF[QN][g][kk] = *(const s16x8*)&shB[slotB * 8192 + rb * 64 +
                                          (((kk * 4 + fq) ^ (rb & 7)) * 8)];
    }
}

template<int QM, int QN>
__device__ __forceinline__ void do_mfma(f32x4 acc[8][4], const s16x8 aF[4][2],
                                        const s16x8 bF[2][2][2]) {
#pragma unroll
  for (int kk = 0; kk < 2; ++kk)
#pragma unroll
    for (int gm = 0; gm < 4; ++gm)
#pragma unroll
      for (int gn = 0; gn < 2; ++gn)
        acc[QM * 4 + gm][QN * 2 + gn] =
            mfma_bf16(aF[gm][kk], bF[QN][gn][kk], acc[QM * 4 + gm][QN * 2 + gn]);
}

// MODE 0: A = xb gathered, K=2048, B=WguT -> a_pair (gelu*up, bf16)
// MODE 1: A = a_pair, K=1024, B=WdT -> d_pair bf16 (w applied) or atomics
template<int MODE>
__device__ __forceinline__ void do_gemm(unsigned short* smem, int item,
              const unsigned short* __restrict__ Asrc,
              const unsigned short* __restrict__ Bsrc,
              const int* __restrict__ pair_token,
              const float* __restrict__ pair_weight,
              const int* __restrict__ tile_expert,
              const int* __restrict__ tile_pos,
              unsigned short* __restrict__ a_out,
              unsigned short* __restrict__ d_pair,
              float* __restrict__ out,
              int* __restrict__ done1, int* __restrict__ g2done,
              int use_dpair) {
  constexpr int KD = (MODE == 0) ? H_DIM : I_DIM;
  constexpr int NT = KD / BK;

  const int mt = item >> 3;
  const int nt = item & 7;
  const int e = tile_expert[mt];
  const int tid = threadIdx.x;
  if (e < 0) {
    if constexpr (MODE == 1)
      if (tid == 0)
        __hip_atomic_fetch_add(g2done, 1, __ATOMIC_RELAXED, __HIP_MEMORY_SCOPE_AGENT);
    return;
  }
  const int pbase = tile_pos[mt];

  if constexpr (MODE == 1) {
    // wait for all 8 GEMM1 items of this mt (a_pair rows ready)
    if (tid == 0) {
      while (__hip_atomic_load(done1 + mt, __ATOMIC_RELAXED,
                               __HIP_MEMORY_SCOPE_AGENT) < 8)
        __builtin_amdgcn_s_sleep(16);
    }
    __syncthreads();
    __builtin_amdgcn_fence(__ATOMIC_ACQUIRE, "agent");
  }

  unsigned short* shA = smem;
  unsigned short* shB = smem + 4 * 8192;

  const int wv = tid >> 6;
  const int lane = tid & 63;
  const int fr = lane & 15;
  const int fq = lane >> 4;
  const int wm = (wv >> 2) * 128;
  const int wn = (wv & 3) * 64;
  const int hA = wv >> 2;
  const int hB = (wv & 3) >> 1;
  const int wn64 = wn & 64;

  const int rbase = wv * 8 + (lane >> 3);
  const int ch = (lane & 7) ^ ((lane >> 3) & 7);
  const unsigned short *srcA00, *srcA01, *srcA10, *srcA11;
  if constexpr (MODE == 0) {
    srcA00 = Asrc + (size_t)pair_token[pbase + rbase] * KD + ch * 8;
    srcA01 = Asrc + (size_t)pair_token[pbase + 64 + rbase] * KD + ch * 8;
    srcA10 = Asrc + (size_t)pair_token[pbase + 128 + rbase] * KD + ch * 8;
    srcA11 = Asrc + (size_t)pair_token[pbase + 192 + rbase] * KD + ch * 8;
  } else {
    srcA00 = Asrc + (size_t)(pbase + rbase) * KD + ch * 8;
    srcA01 = Asrc + (size_t)(pbase + 64 + rbase) * KD + ch * 8;
    srcA10 = Asrc + (size_t)(pbase + 128 + rbase) * KD + ch * 8;
    srcA11 = Asrc + (size_t)(pbase + 192 + rbase) * KD + ch * 8;
  }
  const unsigned short* Be = Bsrc + (size_t)e * 2048 * KD;
  const int nbase = nt * 256 + rbase;
  const unsigned short* srcB00 = Be + (size_t)nbase * KD + ch * 8;
  const unsigned short* srcB01 = Be + (size_t)(nbase + 64) * KD + ch * 8;
  const unsigned short* srcB10 = Be + (size_t)(nbase + 128) * KD + ch * 8;
  const unsigned short* srcB11 = Be + (size_t)(nbase + 192) * KD + ch * 8;

  f32x4 acc[8][4] = {};
  s16x8 aF[4][2];
  s16x8 bF[2][2][2];

  stage2(shA + 0 * 8192 + wv * 512, srcA00, srcA01);
  stage2(shA + 1 * 8192 + wv * 512, srcA10, srcA11);
  stage2(shB + 0 * 8192 + wv * 512, srcB00, srcB01);
  stage2(shB + 1 * 8192 + wv * 512, srcB10, srcB11);
  stage2(shB + 2 * 8192 + wv * 512, srcB00 + BK, srcB01 + BK);
  stage2(shB + 3 * 8192 + wv * 512, srcB10 + BK, srcB11 + BK);
  asm volatile("s_waitcnt vmcnt(4)" ::: "memory");
  __builtin_amdgcn_s_barrier();

  for (int t = 0; t < NT; ++t) {
    const int slotA = (2 * t + hA) & 3;
    const int slotB = (2 * t + hB) & 3;
    lds_a<0>(shA, slotA, wm, fr, fq, aF);
    lds_b<0>(shB, slotB, wn64, fr, fq, bF);
    if (t + 1 < NT)
      stage2(shA + ((2 * (t + 1)) & 3) * 8192 + wv * 512,
             srcA00 + (size_t)(t + 1) * BK, srcA01 + (size_t)(t + 1) * BK);
    __builtin_amdgcn_s_barrier();
    __builtin_amdgcn_s_setprio(1);
    do_mfma<0, 0>(acc, aF, bF);
    __builtin_amdgcn_s_setprio(0);
    __builtin_amdgcn_s_barrier();

    lds_b<1>(shB, slotB, wn64, fr, fq, bF);
    if (t + 1 < NT)
      stage2(shA + ((2 * (t + 1) + 1) & 3) * 8192 + wv * 512,
             srcA10 + (size_t)(t + 1) * BK, srcA11 + (size_t)(t + 1) * BK);
    __builtin_amdgcn_s_barrier();
    __builtin_amdgcn_s_setprio(1);
    do_mfma<0, 1>(acc, aF, bF);
    __builtin_amdgcn_s_setprio(0);
    __builtin_amdgcn_s_barrier();

    lds_a<1>(shA, slotA, wm, fr, fq, aF);
    if (t + 2 < NT)
      stage2(shB + ((2 * (t + 2)) & 3) * 8192 + wv * 512,
             srcB00 + (size_t)(t + 2) * BK, srcB01 + (size_t)(t + 2) * BK);
    __builtin_amdgcn_s_barrier();
    __builtin_amdgcn_s_setprio(1);
    do_mfma<1, 1>(acc, aF, bF);
    __builtin_amdgcn_s_setprio(0);
    __builtin_amdgcn_s_barrier();

    if (t + 2 < NT)
      stage2(shB + ((2 * (t + 2) + 1) & 3) * 8192 + wv * 512,
             srcB10 + (size_t)(t + 2) * BK, srcB11 + (size_t)(t + 2) * BK);
    if (t < NT - 2)       asm volatile("s_waitcnt vmcnt(4)" ::: "memory");
    else if (t == NT - 2) asm volatile("s_waitcnt vmcnt(0)" ::: "memory");
    __builtin_amdgcn_s_barrier();
    __builtin_amdgcn_s_setprio(1);
    do_mfma<1, 0>(acc, aF, bF);
    __builtin_amdgcn_s_setprio(0);
    __builtin_amdgcn_s_barrier();
  }

  if constexpr (MODE == 0) {
    const int colbase = nt * 128 + (wn >> 5) * 16;
#pragma unroll
    for (int am = 0; am < 8; ++am) {
      const int r0e = pbase + wm + am * 16 + fq * 4;
#pragma unroll
      for (int q = 0; q < 2; ++q)
#pragma unroll
        for (int jj = 0; jj < 4; ++jj) {
          const float g = acc[am][2 * q][jj];
          const float u = acc[am][2 * q + 1][jj];
          const float zz = 0.7978845608028654f * (g + 0.044715f * g * g * g);
          const float ex = __expf(2.f * zz);
          const float th = (ex - 1.f) / (ex + 1.f);
          a_out[(size_t)(r0e + jj) * I_DIM + colbase + q * 16 + fr] =
              f2bf(0.5f * g * (1.f + th) * u);
        }
    }
    __syncthreads();   // drain stores, then publish
    if (tid == 0)
      __hip_atomic_fetch_add(done1 + mt, 1, __ATOMIC_RELEASE,
                             __HIP_MEMORY_SCOPE_AGENT);
  } else {
    if (use_dpair) {
#pragma unroll
      for (int am = 0; am < 8; ++am)
#pragma unroll
        for (int jj = 0; jj < 4; ++jj) {
          const int prow = pbase + wm + am * 16 + fq * 4 + jj;
          const float w = pair_weight[prow];
          unsigned short* dp = d_pair + (size_t)prow * H_DIM + nt * 256 + wn + fr;
#pragma unroll
          for (int an = 0; an < 4; ++an)
            dp[an * 16] = f2bf(w * acc[am][an][jj]);
        }
    } else {
#pragma unroll
      for (int am = 0; am < 8; ++am)
#pragma unroll
        for (int jj = 0; jj < 4; ++jj) {
          const int prow = pbase + wm + am * 16 + fq * 4 + jj;
          const float w = pair_weight[prow];
          if (w != 0.f) {
            const int tok = pair_token[prow];
            float* dp = out + (size_t)tok * H_DIM + nt * 256 + wn + fr;
#pragma unroll
            for (int an = 0; an < 4; ++an)
              atom_add_f32(dp + an * 16, w * acc[am][an][jj]);
          }
        }
    }
    __syncthreads();
    if (tid == 0)
      __hip_atomic_fetch_add(g2done, 1, __ATOMIC_RELEASE,
                             __HIP_MEMORY_SCOPE_AGENT);
  }
}

__device__ __forceinline__ float bflo(unsigned int u) {
  return __uint_as_float(u << 16);
}
__device__ __forceinline__ float bfhi(unsigned int u) {
  return __uint_as_float(u & 0xFFFF0000u);
}

__device__ __forceinline__ void do_combine(int c,
              const unsigned short* __restrict__ d_pair,
              const int* __restrict__ inv,
              float* __restrict__ out,
              int* __restrict__ g2done, int use_dpair) {
  if (!use_dpair) return;   // atomic fallback already wrote out
  if (threadIdx.x == 0) {
    while (__hip_atomic_load(g2done, __ATOMIC_RELAXED,
                             __HIP_MEMORY_SCOPE_AGENT) < NG2)
      __builtin_amdgcn_s_sleep(16);
  }
  __syncthreads();
  __builtin_amdgcn_fence(__ATOMIC_ACQUIRE, "agent");

  const int lt = threadIdx.x >> 5;      // 0..15 token within chunk
  const int ln = threadIdx.x & 31;      // 32 threads per token
  const int tt = c * 16 + lt;
  const int p0 = inv[2 * tt], p1 = inv[2 * tt + 1];
  const uint4* r0 = (const uint4*)(d_pair + (size_t)p0 * H_DIM);
  const uint4* r1 = (const uint4*)(d_pair + (size_t)p1 * H_DIM);
  float4* o = (float4*)(out + (size_t)tt * H_DIM);
#pragma unroll
  for (int j = 0; j < 8; ++j) {
    const int cb = ln * 8 + j * 256;    // 8 cols per chunk
    const uint4 a = r0[ln + j * 32];
    const uint4 b = r1[ln + j * 32];
    float4 fa, fb;
    fa.x = bflo(a.x) + bflo(b.x); fa.y = bfhi(a.x) + bfhi(b.x);
    fa.z = bflo(a.y) + bflo(b.y); fa.w = bfhi(a.y) + bfhi(b.y);
    fb.x = bflo(a.z) + bflo(b.z); fb.y = bfhi(a.z) + bfhi(b.z);
    fb.z = bflo(a.w) + bflo(b.w); fb.w = bfhi(a.w) + bfhi(b.w);
    o[cb >> 2] = fa;
    o[(cb >> 2) + 1] = fb;
  }
}

// ------------------------------------------------- persistent fused kernel --
__global__ __launch_bounds__(512, 1)
void moe_fused(const unsigned short* __restrict__ xb,
               const unsigned short* __restrict__ WguT,
               const unsigned short* __restrict__ WdT,
               unsigned short* __restrict__ a_pair,
               unsigned short* __restrict__ d_pair,
               const int* __restrict__ pair_token,
               const float* __restrict__ pair_weight,
               const int* __restrict__ inv,
               const int* __restrict__ tile_expert,
               const int* __restrict__ tile_pos,
               int* __restrict__ ctrl,
               float* __restrict__ out,
               int use_dpair) {
  extern __shared__ unsigned short smem[];
  __shared__ int sItem;
  int* qhead = ctrl;
  int* g2done = ctrl + 1;
  int* done1 = ctrl + 2;
  for (;;) {
    __syncthreads();
    if (threadIdx.x == 0) sItem = atomicAdd(qhead, 1);
    __syncthreads();
    const int item = sItem;
    if (item >= NITEMS) return;
    if (item < NG1) {
      do_gemm<0>(smem, item, xb, WguT, pair_token, pair_weight, tile_expert,
                 tile_pos, a_pair, d_pair, out, done1, g2done, use_dpair);
    } else if (item < NG1 + NG2) {
      do_gemm<1>(smem, item - NG1, a_pair, WdT, pair_token, pair_weight,
                 tile_expert, tile_pos, a_pair, d_pair, out, done1, g2done,
                 use_dpair);
    } else {
      do_combine(item - NG1 - NG2, d_pair, inv, out, g2done, use_dpair);
    }
  }
}

// ------------------------------------------------------------------ launch --
extern "C" void kernel_launch(void* const* d_in, const int* in_sizes, int n_in,
                              void* d_out, int out_size, void* d_ws, size_t ws_size,
                              hipStream_t stream) {
  const float* x  = (const float*)d_in[0];
  const float* Wg = (const float*)d_in[1];
  const float* Wu = (const float*)d_in[2];
  const float* Wd = (const float*)d_in[3];
  const int*   sel = (const int*)d_in[4];
  const float* rw  = (const float*)d_in[5];
  float* out = (float*)d_out;

  char* base = (char*)d_ws;
  size_t off = 0;
  auto take = [&](size_t bytes) { char* p = base + off; off += bytes; return p; };
  unsigned short* xb     = (unsigned short*)take((size_t)T_TOK * H_DIM * 2);
  unsigned short* WguT   = (unsigned short*)take((size_t)E_NUM * 2048 * 2048 * 2);
  unsigned short* WdT    = (unsigned short*)take((size_t)E_NUM * H_DIM * I_DIM * 2);
  unsigned short* a_pair = (unsigned short*)take((size_t)CAP * I_DIM * 2);
  int*   pair_token  = (int*)take(CAP * 4);
  float* pair_weight = (float*)take(CAP * 4);
  int*   inv         = (int*)take(NPAIR * 4);
  int*   tile_expert = (int*)take(256);
  int*   tile_pos    = (int*)take(256);
  int*   ctrl        = (int*)take(256);
  size_t dpair_bytes = (size_t)CAP * H_DIM * 2;
  int use_dpair = (off + dpair_bytes <= ws_size) ? 1 : 0;
  unsigned short* d_pair = use_dpair ? (unsigned short*)take(dpair_bytes)
                                     : (unsigned short*)base;

  hipFuncSetAttribute((const void*)&moe_fused,
                      hipFuncAttributeMaxDynamicSharedMemorySize, 131072);

  routing_kernel<<<1, 512, 0, stream>>>(sel, rw, pair_token, pair_weight, inv,
                                        tile_expert, tile_pos, ctrl);
  prep_kernel<<<2048, 256, 0, stream>>>((const float4*)x, (ushort4*)xb,
                                        (float4*)out, (T_TOK * H_DIM) / 4);
  transpose_all<<<dim3(512, 24), 256, 0, stream>>>(Wg, Wu, Wd, WguT, WdT);

  moe_fused<<<256, 512, 131072, stream>>>(xb, WguT, WdT, a_pair, d_pair,
                                          pair_token, pair_weight, inv,
                                          tile_expert, tile_pos, ctrl, out,
                                          use_dpair);
}

// Round 4
// 282.369 us; speedup vs baseline: 2.3030x; 2.3030x over previous
//
#include <hip/hip_runtime.h>
#include <hip/hip_bf16.h>
#include <stdint.h>

#define T_TOK 4096
#define H_DIM 2048
#define I_DIM 1024
#define E_NUM 8
#define NPAIR 8192            // T_TOK * K_SEL
#define BM 128
#define MAX_TILES 72          // worst case sum(ceil(cnt_e/128)) = 64 + 8
#define CAP (MAX_TILES * BM)  // 9216 padded pair slots
#define NTB (MAX_TILES * 16)  // gemm blocks per dispatch = 1152
#define TDBLKS 4096           // transpose-d blocks appended to GEMM1

typedef short s16x8 __attribute__((ext_vector_type(8)));
typedef __bf16 bf16x8 __attribute__((ext_vector_type(8)));
typedef float f32x4 __attribute__((ext_vector_type(4)));

using gas1_t = const __attribute__((address_space(1))) void*;
using las3_t = __attribute__((address_space(3))) void*;

__device__ __forceinline__ void async_lds16(const void* g, void* l) {
  __builtin_amdgcn_global_load_lds((gas1_t)(uintptr_t)g,
                                   (las3_t)(uint32_t)(uintptr_t)l, 16, 0, 0);
}

__device__ __forceinline__ unsigned short f2bf(float f) {
  union { float f; unsigned int u; } v; v.f = f;
  unsigned int r = v.u + 0x7FFF + ((v.u >> 16) & 1); // RNE
  return (unsigned short)(r >> 16);
}

__device__ __forceinline__ f32x4 mfma_bf16(s16x8 a, s16x8 b, f32x4 c) {
  return __builtin_amdgcn_mfma_f32_16x16x32_bf16(
      __builtin_bit_cast(bf16x8, a), __builtin_bit_cast(bf16x8, b), c, 0, 0, 0);
}

__device__ __forceinline__ void atom_add_f32(float* p, float v) {
#if defined(__gfx950__) || defined(__gfx942__) || defined(__gfx90a__)
  unsafeAtomicAdd(p, v);
#else
  atomicAdd(p, v);
#endif
}

__device__ __forceinline__ unsigned short gelu_mul_bf16(float g, float u) {
  const float z = 0.7978845608028654f * (g + 0.044715f * g * g * g);
  const float ex = __expf(2.f * z);
  const float th = (ex - 1.f) / (ex + 1.f);
  return f2bf(0.5f * g * (1.f + th) * u);
}

// ========================= prep: zero + cvt + transpose(gu) + routing ======
// grid = 1024 (cvt/zero) + 4096 (gu transpose, 2 subtiles each) + 1 (routing)
__global__ __launch_bounds__(512)
void prep_all(const float4* __restrict__ x4, ushort4* __restrict__ xb4,
              float4* __restrict__ out4,
              const float* __restrict__ Wg, const float* __restrict__ Wu,
              unsigned short* __restrict__ WguT,
              const int* __restrict__ sel, const float* __restrict__ rw,
              int* __restrict__ pair_token, float* __restrict__ pair_weight,
              int* __restrict__ tile_expert, int* __restrict__ tile_pos) {
  const int bid = blockIdx.x;
  const int tid = threadIdx.x;

  if (bid < 1024) {                       // ---- zero out + cvt x ----
    const float4 z = make_float4(0.f, 0.f, 0.f, 0.f);
    int i = bid * 512 + tid;
    const int stride = 1024 * 512;
#pragma unroll
    for (int q = 0; q < 4; ++q) {
      out4[i] = z;
      const float4 v = x4[i];
      ushort4 r;
      r.x = f2bf(v.x); r.y = f2bf(v.y); r.z = f2bf(v.z); r.w = f2bf(v.w);
      xb4[i] = r;
      i += stride;
    }
    return;
  }

  if (bid < 1024 + 4096) {                // ---- transpose Wg/Wu -> WguT ----
    __shared__ unsigned short Tl[2][64][72];
    const int sub = tid >> 8, k = tid & 255;
    const int t3 = (bid - 1024) * 2 + sub;    // [0, 8192)
    const int which = t3 >> 12;               // 0=gate, 1=up
    const int e = (t3 >> 9) & 7;
    const int tile = t3 & 511;                // 32 h-tiles x 16 i-tiles
    const int r0 = (tile >> 4) * 64;          // h base
    const int c0 = (tile & 15) * 64;          // i base
    const float* src = (which ? Wu : Wg) + (size_t)e * H_DIM * I_DIM;
    const int rr = k >> 2, cb = (k & 3) * 16;
    const float4* s4 = (const float4*)(src + (size_t)(r0 + rr) * I_DIM + c0 + cb);
    unsigned short* dl = &Tl[sub][rr][cb];
#pragma unroll
    for (int q = 0; q < 4; ++q) {
      const float4 v = s4[q];
      dl[q * 4 + 0] = f2bf(v.x); dl[q * 4 + 1] = f2bf(v.y);
      dl[q * 4 + 2] = f2bf(v.z); dl[q * 4 + 3] = f2bf(v.w);
    }
    __syncthreads();
    const int oc = k >> 2, rb = (k & 3) * 16;
    union { unsigned short us[16]; uint4 u4[2]; } pk;
#pragma unroll
    for (int m = 0; m < 16; ++m) pk.us[m] = Tl[sub][rb + m][oc];
    const int gi = c0 + oc;
    const int orow = (gi >> 4) * 32 + (gi & 15) + which * 16;  // g/u interleave
    unsigned short* dst = WguT + ((size_t)e * 2048 + orow) * H_DIM + r0 + rb;
    uint4* d4 = (uint4*)dst;
    d4[0] = pk.u4[0]; d4[1] = pk.u4[1];
    return;
  }

  // ---- routing (single block) ----
  __shared__ int cnt[E_NUM], off[E_NUM], fil[E_NUM];
  if (tid < E_NUM) { cnt[tid] = 0; fil[tid] = 0; }
  __syncthreads();
  for (int p = tid; p < NPAIR; p += 512) atomicAdd(&cnt[sel[p]], 1);
  for (int q = tid; q < CAP; q += 512) { pair_token[q] = 0; pair_weight[q] = 0.f; }
  __syncthreads();
  if (tid == 0) {
    int run = 0, idx = 0;
    for (int e = 0; e < E_NUM; ++e) {
      off[e] = run;
      const int nt = (cnt[e] + BM - 1) / BM;
      for (int t = 0; t < nt; ++t) { tile_expert[idx] = e; tile_pos[idx] = run + t * BM; ++idx; }
      run += nt * BM;
    }
    for (; idx < MAX_TILES; ++idx) tile_expert[idx] = -1;
  }
  __syncthreads();
  for (int p = tid; p < NPAIR; p += 512) {
    const int e = sel[p];
    const int pos = off[e] + atomicAdd(&fil[e], 1);
    pair_token[pos] = p >> 1;   // K_SEL == 2
    pair_weight[pos] = rw[p];
  }
}

// ========================= transpose Wd -> WdT (i-permuted cols) ===========
// i' = (i>>5)*32 + (i&15)*2 + ((i>>4)&1)  (matches GEMM1's packed epilogue)
__device__ void transpose_d_block(int idx, const float* __restrict__ Wd,
                                  unsigned short* __restrict__ WdT,
                                  unsigned short* Tl /* >= 64*72 shorts */) {
  const int k = threadIdx.x;                  // 256 threads
  const int e = idx >> 9;                     // [0,4096) -> 8 experts x 512
  const int tile = idx & 511;
  const int r0 = (tile >> 5) * 64;            // i base (16 tiles)
  const int c0 = (tile & 31) * 64;            // h base (32 tiles)
  const float* src = Wd + (size_t)e * I_DIM * H_DIM;
  const int rr = k >> 2, cb = (k & 3) * 16;
  const float4* s4 = (const float4*)(src + (size_t)(r0 + rr) * H_DIM + c0 + cb);
  unsigned short* dl = Tl + rr * 72 + cb;
#pragma unroll
  for (int q = 0; q < 4; ++q) {
    const float4 v = s4[q];
    dl[q * 4 + 0] = f2bf(v.x); dl[q * 4 + 1] = f2bf(v.y);
    dl[q * 4 + 2] = f2bf(v.z); dl[q * 4 + 3] = f2bf(v.w);
  }
  __syncthreads();
  const int oc = k >> 2, rb = (k & 3) * 16;
  const int gh = c0 + oc;
  union { unsigned short us[16]; uint4 u4[2]; } pk;
#pragma unroll
  for (int m = 0; m < 16; ++m) {
    const int il = rb + m;                                   // i' local [0,64)
    const int isrc = (il & 32) + ((il & 1) << 4) + ((il >> 1) & 15);  // inv perm
    pk.us[m] = Tl[isrc * 72 + oc];
  }
  unsigned short* dst = WdT + ((size_t)e * H_DIM + gh) * I_DIM + r0 + rb;
  uint4* d4 = (uint4*)dst;
  d4[0] = pk.u4[0]; d4[1] = pk.u4[1];
}

// ========================= 128x128 dbuf GEMM ===============================
// MODE 0: A = xb gathered by pair_token (K=2048), B = WguT -> a_pair packed u32
//         (+ transpose-d tail blocks)
// MODE 1: A = a_pair (K=1024, i' order), B = WdT -> atomic scatter into out
template<int MODE>
__global__ __launch_bounds__(256, 2)
void moe_gemm(const unsigned short* __restrict__ Aop,
              const unsigned short* __restrict__ Bop,
              const float* __restrict__ Wd,
              unsigned short* __restrict__ WdT,
              const int* __restrict__ pair_token,
              const float* __restrict__ pair_weight,
              const int* __restrict__ tile_expert,
              const int* __restrict__ tile_pos,
              unsigned int* __restrict__ a32,
              float* __restrict__ out) {
  constexpr int KD = (MODE == 0) ? H_DIM : I_DIM;
  constexpr int NT = KD / 64;

  extern __shared__ unsigned short smem[];   // 2 x 16KB A slots + 2 x 16KB B slots
  const int bid = blockIdx.x;

  if constexpr (MODE == 0) {
    if (bid >= NTB) { transpose_d_block(bid - NTB, Wd, WdT, smem); return; }
  }

  const int mt = bid % MAX_TILES;
  const int nt = bid / MAX_TILES;             // [0,16)
  const int e = tile_expert[mt];
  if (e < 0) return;
  const int pbase = tile_pos[mt];

  const int tid = threadIdx.x;
  const int wv = tid >> 6;                    // 0..3
  const int lane = tid & 63;
  const int fr = lane & 15;
  const int fq = lane >> 4;
  const int wm = (wv >> 1) * 64;              // 0/64
  const int wnh = wv & 1;                     // 0/1 -> wn = wnh*64

  unsigned short* sA = smem;                  // slots at 0, 8192 (shorts)
  unsigned short* sB = smem + 2 * 8192;       // slots at 0, 8192

  // ---- staging sources: 4 calls/operand/wave; call j covers rows (wv*4+j)*8+(l>>3)
  const int rloc = lane >> 3;                 // 0..7
  const int gch = (lane & 7) ^ rloc;          // row&7 == rloc for all calls
  const unsigned short* pa[4];
  const unsigned short* pb[4];
#pragma unroll
  for (int j = 0; j < 4; ++j) {
    const int row = (wv * 4 + j) * 8 + rloc;  // 0..127
    size_t arow;
    if constexpr (MODE == 0) arow = (size_t)pair_token[pbase + row];
    else                     arow = (size_t)(pbase + row);
    pa[j] = Aop + arow * KD + gch * 8;
    pb[j] = Bop + ((size_t)e * 2048 + nt * 128 + row) * KD + gch * 8;
  }

  // ---- LDS fragment offsets (shorts); row stride = 64 shorts (128B)
  int aoff[4][2], boff[4][2];
#pragma unroll
  for (int mf = 0; mf < 4; ++mf)
#pragma unroll
    for (int kk = 0; kk < 2; ++kk) {
      const int ra = wm + mf * 16 + fr;
      aoff[mf][kk] = ra * 64 + (((kk * 4 + fq) ^ (ra & 7)) * 8);
      const int rb = wnh * 64 + mf * 16 + fr;
      boff[mf][kk] = rb * 64 + (((kk * 4 + fq) ^ (rb & 7)) * 8);
    }

  f32x4 acc[4][4] = {};

#define STAGE(T, S)                                                          \
  {                                                                          \
    const int _o = (S) * 8192 + wv * 2048;                                   \
    _Pragma("unroll")                                                        \
    for (int j = 0; j < 4; ++j) {                                            \
      async_lds16(pa[j] + (size_t)(T) * 64, sA + _o + j * 512);              \
      async_lds16(pb[j] + (size_t)(T) * 64, sB + _o + j * 512);              \
    }                                                                        \
  }

  STAGE(0, 0);
  asm volatile("s_waitcnt vmcnt(0)" ::: "memory");
  __builtin_amdgcn_s_barrier();

  for (int t = 0; t < NT; ++t) {
    const int s = t & 1;
    if (t + 1 < NT) STAGE(t + 1, s ^ 1);
    s16x8 aF[4][2], bF[4][2];
    const unsigned short* pAs = sA + s * 8192;
    const unsigned short* pBs = sB + s * 8192;
#pragma unroll
    for (int mf = 0; mf < 4; ++mf)
#pragma unroll
      for (int kk = 0; kk < 2; ++kk) {
        aF[mf][kk] = *(const s16x8*)&pAs[aoff[mf][kk]];
        bF[mf][kk] = *(const s16x8*)&pBs[boff[mf][kk]];
      }
    __builtin_amdgcn_s_setprio(1);
#pragma unroll
    for (int kk = 0; kk < 2; ++kk)
#pragma unroll
      for (int mf = 0; mf < 4; ++mf)
#pragma unroll
        for (int nf = 0; nf < 4; ++nf)
          acc[mf][nf] = mfma_bf16(aF[mf][kk], bF[nf][kk], acc[mf][nf]);
    __builtin_amdgcn_s_setprio(0);
    asm volatile("s_waitcnt vmcnt(0)" ::: "memory");
    __builtin_amdgcn_s_barrier();
  }
#undef STAGE

  if constexpr (MODE == 0) {
    // packed epilogue: acc cols (0,1)=(g,u) of i0, (2,3)=(g,u) of i1=i0+16
    // i0' = 2*fr, i1' = 2*fr+1 within 32-block (nt*64 + wnh*32)
    const int cidx = nt * 32 + wnh * 16 + fr;   // dword index within row
#pragma unroll
    for (int mf = 0; mf < 4; ++mf)
#pragma unroll
      for (int jj = 0; jj < 4; ++jj) {
        const int row = pbase + wm + mf * 16 + fq * 4 + jj;
        const unsigned int h0 = gelu_mul_bf16(acc[mf][0][jj], acc[mf][1][jj]);
        const unsigned int h1 = gelu_mul_bf16(acc[mf][2][jj], acc[mf][3][jj]);
        a32[(size_t)row * (I_DIM / 2) + cidx] = h0 | (h1 << 16);
      }
  } else {
#pragma unroll
    for (int mf = 0; mf < 4; ++mf)
#pragma unroll
      for (int jj = 0; jj < 4; ++jj) {
        const int prow = pbase + wm + mf * 16 + fq * 4 + jj;
        const float w = pair_weight[prow];
        if (w != 0.f) {
          const int tok = pair_token[prow];
          float* dp = out + (size_t)tok * H_DIM + nt * 128 + wnh * 64 + fr;
#pragma unroll
          for (int nf = 0; nf < 4; ++nf)
            atom_add_f32(dp + nf * 16, w * acc[mf][nf][jj]);
        }
      }
  }
}

// ================================= launch ==================================
extern "C" void kernel_launch(void* const* d_in, const int* in_sizes, int n_in,
                              void* d_out, int out_size, void* d_ws, size_t ws_size,
                              hipStream_t stream) {
  const float* x  = (const float*)d_in[0];
  const float* Wg = (const float*)d_in[1];
  const float* Wu = (const float*)d_in[2];
  const float* Wd = (const float*)d_in[3];
  const int*   sel = (const int*)d_in[4];
  const float* rw  = (const float*)d_in[5];
  float* out = (float*)d_out;

  char* base = (char*)d_ws;
  size_t off = 0;
  auto take = [&](size_t bytes) { char* p = base + off; off += bytes; return p; };
  unsigned short* xb     = (unsigned short*)take((size_t)T_TOK * H_DIM * 2);
  unsigned short* WguT   = (unsigned short*)take((size_t)E_NUM * 2048 * H_DIM * 2);
  unsigned short* WdT    = (unsigned short*)take((size_t)E_NUM * H_DIM * I_DIM * 2);
  unsigned short* a_pair = (unsigned short*)take((size_t)CAP * I_DIM * 2);
  int*   pair_token  = (int*)take(CAP * 4);
  float* pair_weight = (float*)take(CAP * 4);
  int*   tile_expert = (int*)take(512);
  int*   tile_pos    = (int*)take(512);
  (void)off;

  hipFuncSetAttribute((const void*)&moe_gemm<0>,
                      hipFuncAttributeMaxDynamicSharedMemorySize, 65536);
  hipFuncSetAttribute((const void*)&moe_gemm<1>,
                      hipFuncAttributeMaxDynamicSharedMemorySize, 65536);

  prep_all<<<1024 + 4096 + 1, 512, 0, stream>>>(
      (const float4*)x, (ushort4*)xb, (float4*)out, Wg, Wu, WguT, sel, rw,
      pair_token, pair_weight, tile_expert, tile_pos);

  moe_gemm<0><<<NTB + TDBLKS, 256, 65536, stream>>>(
      xb, WguT, Wd, WdT, pair_token, pair_weight, tile_expert, tile_pos,
      (unsigned int*)a_pair, nullptr);

  moe_gemm<1><<<NTB, 256, 65536, stream>>>(
      a_pair, WdT, nullptr, nullptr, pair_token, pair_weight, tile_expert,
      tile_pos, nullptr, out);
}

// Round 5
// 251.259 us; speedup vs baseline: 2.5882x; 1.1238x over previous
//
#include <hip/hip_runtime.h>
#include <hip/hip_bf16.h>
#include <stdint.h>

#define T_TOK 4096
#define H_DIM 2048
#define I_DIM 1024
#define E_NUM 8
#define NPAIR 8192            // T_TOK * K_SEL
#define BM 128
#define MAX_TILES 72          // worst case sum(ceil(cnt_e/128)) = 64 + 8
#define CAP (MAX_TILES * BM)  // 9216 padded pair slots
#define NTB (MAX_TILES * 16)  // gemm blocks per dispatch = 1152

// prep_all grid layout
#define CVT_BLKS 1024
#define GU_BLKS 4096          // 8192 gu 64x64 tiles, 2 per block
#define D_BLKS 2048           // 4096 d 64x64 tiles, 2 per block
#define PREP_BLKS (CVT_BLKS + GU_BLKS + D_BLKS + 1)

typedef short s16x8 __attribute__((ext_vector_type(8)));
typedef __bf16 bf16x8 __attribute__((ext_vector_type(8)));
typedef float f32x4 __attribute__((ext_vector_type(4)));

using gas1_t = const __attribute__((address_space(1))) void*;
using las3_t = __attribute__((address_space(3))) void*;

__device__ __forceinline__ void async_lds16(const void* g, void* l) {
  __builtin_amdgcn_global_load_lds((gas1_t)(uintptr_t)g,
                                   (las3_t)(uint32_t)(uintptr_t)l, 16, 0, 0);
}

__device__ __forceinline__ unsigned short f2bf(float f) {
  union { float f; unsigned int u; } v; v.f = f;
  unsigned int r = v.u + 0x7FFF + ((v.u >> 16) & 1); // RNE
  return (unsigned short)(r >> 16);
}

__device__ __forceinline__ f32x4 mfma_bf16(s16x8 a, s16x8 b, f32x4 c) {
  return __builtin_amdgcn_mfma_f32_16x16x32_bf16(
      __builtin_bit_cast(bf16x8, a), __builtin_bit_cast(bf16x8, b), c, 0, 0, 0);
}

__device__ __forceinline__ unsigned short gelu_mul_bf16(float g, float u) {
  const float z = 0.7978845608028654f * (g + 0.044715f * g * g * g);
  const float ex = __expf(2.f * z);
  const float th = (ex - 1.f) / (ex + 1.f);
  return f2bf(0.5f * g * (1.f + th) * u);
}

__device__ __forceinline__ float bflo(unsigned int u) {
  return __uint_as_float(u << 16);
}
__device__ __forceinline__ float bfhi(unsigned int u) {
  return __uint_as_float(u & 0xFFFF0000u);
}

// ===== prep: cvt x + transpose(Wg,Wu->WguT) + transpose(Wd->WdT) + routing ==
// LDS transpose tiles use stride 73 (odd): the four rb-groups land on banks
// 0/8/16/24 -> no LDS bank conflicts on the column reads.
__global__ __launch_bounds__(512)
void prep_all(const float4* __restrict__ x4, ushort4* __restrict__ xb4,
              const float* __restrict__ Wg, const float* __restrict__ Wu,
              const float* __restrict__ Wd,
              unsigned short* __restrict__ WguT,
              unsigned short* __restrict__ WdT,
              const int* __restrict__ sel, const float* __restrict__ rw,
              int* __restrict__ pair_token, float* __restrict__ pair_weight,
              int* __restrict__ inv,
              int* __restrict__ tile_expert, int* __restrict__ tile_pos) {
  const int bid = blockIdx.x;
  const int tid = threadIdx.x;

  if (bid < CVT_BLKS) {                    // ---- cvt x -> bf16 ----
    int i = bid * 512 + tid;
    const int stride = CVT_BLKS * 512;
#pragma unroll
    for (int q = 0; q < 4; ++q) {
      const float4 v = x4[i];
      ushort4 r;
      r.x = f2bf(v.x); r.y = f2bf(v.y); r.z = f2bf(v.z); r.w = f2bf(v.w);
      xb4[i] = r;
      i += stride;
    }
    return;
  }

  if (bid < CVT_BLKS + GU_BLKS + D_BLKS) { // ---- weight transposes ----
    __shared__ unsigned short Tl[2][64 * 73];
    const int sub = tid >> 8, k = tid & 255;
    const int rr = k >> 2, cb = (k & 3) * 16;
    const int oc = k >> 2, rb = (k & 3) * 16;

    if (bid < CVT_BLKS + GU_BLKS) {        // Wg/Wu -> WguT (g/u interleaved)
      const int t3 = (bid - CVT_BLKS) * 2 + sub;    // [0, 8192)
      const int which = t3 >> 12;                   // 0=gate, 1=up
      const int e = (t3 >> 9) & 7;
      const int tile = t3 & 511;                    // 32 h-tiles x 16 i-tiles
      const int r0 = (tile >> 4) * 64;              // h base
      const int c0 = (tile & 15) * 64;              // i base
      const float* src = (which ? Wu : Wg) + (size_t)e * H_DIM * I_DIM;
      const float4* s4 = (const float4*)(src + (size_t)(r0 + rr) * I_DIM + c0 + cb);
      unsigned short* dl = &Tl[sub][rr * 73 + cb];
#pragma unroll
      for (int q = 0; q < 4; ++q) {
        const float4 v = s4[q];
        dl[q * 4 + 0] = f2bf(v.x); dl[q * 4 + 1] = f2bf(v.y);
        dl[q * 4 + 2] = f2bf(v.z); dl[q * 4 + 3] = f2bf(v.w);
      }
      __syncthreads();
      union { unsigned short us[16]; uint4 u4[2]; } pk;
#pragma unroll
      for (int m = 0; m < 16; ++m) pk.us[m] = Tl[sub][(rb + m) * 73 + oc];
      const int gi = c0 + oc;
      const int orow = (gi >> 4) * 32 + (gi & 15) + which * 16;
      uint4* d4 = (uint4*)(WguT + ((size_t)e * 2048 + orow) * H_DIM + r0 + rb);
      d4[0] = pk.u4[0]; d4[1] = pk.u4[1];
    } else {                               // Wd -> WdT (i'-permuted cols)
      const int t3 = (bid - CVT_BLKS - GU_BLKS) * 2 + sub;  // [0, 4096)
      const int e = t3 >> 9;
      const int tile = t3 & 511;                    // 16 i-tiles x 32 h-tiles
      const int r0 = (tile >> 5) * 64;              // i base
      const int c0 = (tile & 31) * 64;              // h base
      const float* src = Wd + (size_t)e * I_DIM * H_DIM;
      const float4* s4 = (const float4*)(src + (size_t)(r0 + rr) * H_DIM + c0 + cb);
      unsigned short* dl = &Tl[sub][rr * 73 + cb];
#pragma unroll
      for (int q = 0; q < 4; ++q) {
        const float4 v = s4[q];
        dl[q * 4 + 0] = f2bf(v.x); dl[q * 4 + 1] = f2bf(v.y);
        dl[q * 4 + 2] = f2bf(v.z); dl[q * 4 + 3] = f2bf(v.w);
      }
      __syncthreads();
      union { unsigned short us[16]; uint4 u4[2]; } pk;
#pragma unroll
      for (int m = 0; m < 16; ++m) {
        const int il = rb + m;                      // i' local [0,64)
        const int isrc = (il & 32) + ((il & 1) << 4) + ((il >> 1) & 15);
        pk.us[m] = Tl[sub][isrc * 73 + oc];
      }
      const int gh = c0 + oc;
      uint4* d4 = (uint4*)(WdT + ((size_t)e * H_DIM + gh) * I_DIM + r0 + rb);
      d4[0] = pk.u4[0]; d4[1] = pk.u4[1];
    }
    return;
  }

  // ---- routing (single block) ----
  __shared__ int cnt[E_NUM], off[E_NUM], fil[E_NUM];
  if (tid < E_NUM) { cnt[tid] = 0; fil[tid] = 0; }
  __syncthreads();
  for (int p = tid; p < NPAIR; p += 512) atomicAdd(&cnt[sel[p]], 1);
  for (int q = tid; q < CAP; q += 512) { pair_token[q] = 0; pair_weight[q] = 0.f; }
  __syncthreads();
  if (tid == 0) {
    int run = 0, idx = 0;
    for (int e = 0; e < E_NUM; ++e) {
      off[e] = run;
      const int nt = (cnt[e] + BM - 1) / BM;
      for (int t = 0; t < nt; ++t) { tile_expert[idx] = e; tile_pos[idx] = run + t * BM; ++idx; }
      run += nt * BM;
    }
    for (; idx < MAX_TILES; ++idx) tile_expert[idx] = -1;
  }
  __syncthreads();
  for (int p = tid; p < NPAIR; p += 512) {
    const int e = sel[p];
    const int pos = off[e] + atomicAdd(&fil[e], 1);
    pair_token[pos] = p >> 1;   // K_SEL == 2
    pair_weight[pos] = rw[p];
    inv[p] = pos;
  }
}

// ========================= 128x128 dbuf GEMM ===============================
// MODE 0: A = xb gathered by pair_token (K=2048), B = WguT -> a_pair packed u32
// MODE 1: A = a_pair (K=1024, i' order), B = WdT -> d_pair bf16 (w applied)
// Block swizzle: XCD-chunked, nt-fastest -> the 16 N-blocks of one mt share
// one XCD's L2 for the A tile; B streams once via L3.
template<int MODE>
__global__ __launch_bounds__(256, 2)
void moe_gemm(const unsigned short* __restrict__ Aop,
              const unsigned short* __restrict__ Bop,
              const int* __restrict__ pair_token,
              const float* __restrict__ pair_weight,
              const int* __restrict__ tile_expert,
              const int* __restrict__ tile_pos,
              unsigned int* __restrict__ a32,
              unsigned short* __restrict__ d_pair) {
  constexpr int KD = (MODE == 0) ? H_DIM : I_DIM;
  constexpr int NT = KD / 64;

  extern __shared__ unsigned short smem[];   // 2 A slots + 2 B slots, 16KB each

  const int bid = blockIdx.x;
  const int lgc = (bid & 7) * (NTB / 8) + (bid >> 3);   // bijective (1152%8==0)
  const int mt = lgc >> 4;
  const int nt = lgc & 15;
  const int e = tile_expert[mt];
  if (e < 0) return;
  const int pbase = tile_pos[mt];

  const int tid = threadIdx.x;
  const int wv = tid >> 6;                    // 0..3
  const int lane = tid & 63;
  const int fr = lane & 15;
  const int fq = lane >> 4;
  const int wm = (wv >> 1) * 64;              // 0/64
  const int wnh = wv & 1;                     // 0/1 -> wn = wnh*64

  unsigned short* sA = smem;                  // slots at 0, 8192 (shorts)
  unsigned short* sB = smem + 2 * 8192;

  // staging sources: 4 calls/operand/wave; call j covers rows (wv*4+j)*8+(l>>3)
  const int rloc = lane >> 3;                 // 0..7
  const int gch = (lane & 7) ^ rloc;          // pre-swizzled chunk (row&7==rloc)
  const unsigned short* pa[4];
  const unsigned short* pb[4];
#pragma unroll
  for (int j = 0; j < 4; ++j) {
    const int row = (wv * 4 + j) * 8 + rloc;  // 0..127
    size_t arow;
    if constexpr (MODE == 0) arow = (size_t)pair_token[pbase + row];
    else                     arow = (size_t)(pbase + row);
    pa[j] = Aop + arow * KD + gch * 8;
    pb[j] = Bop + ((size_t)e * 2048 + nt * 128 + row) * KD + gch * 8;
  }

  // LDS fragment offsets (shorts); row stride = 64 shorts (128B)
  int aoff[4][2], boff[4][2];
#pragma unroll
  for (int mf = 0; mf < 4; ++mf)
#pragma unroll
    for (int kk = 0; kk < 2; ++kk) {
      const int ra = wm + mf * 16 + fr;
      aoff[mf][kk] = ra * 64 + (((kk * 4 + fq) ^ (ra & 7)) * 8);
      const int rb = wnh * 64 + mf * 16 + fr;
      boff[mf][kk] = rb * 64 + (((kk * 4 + fq) ^ (rb & 7)) * 8);
    }

  f32x4 acc[4][4] = {};

#define STAGE(T, S)                                                          \
  {                                                                          \
    const int _o = (S) * 8192 + wv * 2048;                                   \
    _Pragma("unroll")                                                        \
    for (int j = 0; j < 4; ++j) {                                            \
      async_lds16(pa[j] + (size_t)(T) * 64, sA + _o + j * 512);              \
      async_lds16(pb[j] + (size_t)(T) * 64, sB + _o + j * 512);              \
    }                                                                        \
  }

  STAGE(0, 0);
  asm volatile("s_waitcnt vmcnt(0)" ::: "memory");
  __builtin_amdgcn_s_barrier();

  for (int t = 0; t < NT; ++t) {
    const int s = t & 1;
    if (t + 1 < NT) STAGE(t + 1, s ^ 1);
    s16x8 aF[4][2], bF[4][2];
    const unsigned short* pAs = sA + s * 8192;
    const unsigned short* pBs = sB + s * 8192;
#pragma unroll
    for (int mf = 0; mf < 4; ++mf)
#pragma unroll
      for (int kk = 0; kk < 2; ++kk) {
        aF[mf][kk] = *(const s16x8*)&pAs[aoff[mf][kk]];
        bF[mf][kk] = *(const s16x8*)&pBs[boff[mf][kk]];
      }
    __builtin_amdgcn_s_setprio(1);
#pragma unroll
    for (int kk = 0; kk < 2; ++kk)
#pragma unroll
      for (int mf = 0; mf < 4; ++mf)
#pragma unroll
        for (int nf = 0; nf < 4; ++nf)
          acc[mf][nf] = mfma_bf16(aF[mf][kk], bF[nf][kk], acc[mf][nf]);
    __builtin_amdgcn_s_setprio(0);
    asm volatile("s_waitcnt vmcnt(0)" ::: "memory");
    __builtin_amdgcn_s_barrier();
  }
#undef STAGE

  if constexpr (MODE == 0) {
    // packed epilogue: acc cols (0,1)=(g,u) of i0, (2,3)=(g,u) of i1=i0+16
    const int cidx = nt * 32 + wnh * 16 + fr;   // dword index within row
#pragma unroll
    for (int mf = 0; mf < 4; ++mf)
#pragma unroll
      for (int jj = 0; jj < 4; ++jj) {
        const int row = pbase + wm + mf * 16 + fq * 4 + jj;
        const unsigned int h0 = gelu_mul_bf16(acc[mf][0][jj], acc[mf][1][jj]);
        const unsigned int h1 = gelu_mul_bf16(acc[mf][2][jj], acc[mf][3][jj]);
        a32[(size_t)row * (I_DIM / 2) + cidx] = h0 | (h1 << 16);
      }
  } else {
    // plain bf16 stores of w*d into d_pair (combine sums the two experts)
#pragma unroll
    for (int mf = 0; mf < 4; ++mf)
#pragma unroll
      for (int jj = 0; jj < 4; ++jj) {
        const int prow = pbase + wm + mf * 16 + fq * 4 + jj;
        const float w = pair_weight[prow];
        unsigned short* dp = d_pair + (size_t)prow * H_DIM + nt * 128 + wnh * 64 + fr;
#pragma unroll
        for (int nf = 0; nf < 4; ++nf)
          dp[nf * 16] = f2bf(w * acc[mf][nf][jj]);
      }
  }
}

// ========================= combine: out[t] = d[p0] + d[p1] =================
__global__ __launch_bounds__(256)
void combine(const unsigned short* __restrict__ d_pair,
             const int* __restrict__ inv,
             float* __restrict__ out) {
  const int tid = threadIdx.x;
  const int tok = blockIdx.x * 2 + (tid >> 7);
  const int ln = tid & 127;
  const int p0 = inv[2 * tok], p1 = inv[2 * tok + 1];
  const uint4* r0 = (const uint4*)(d_pair + (size_t)p0 * H_DIM);
  const uint4* r1 = (const uint4*)(d_pair + (size_t)p1 * H_DIM);
  float4* o = (float4*)(out + (size_t)tok * H_DIM);
#pragma unroll
  for (int j = 0; j < 2; ++j) {
    const int c = ln + j * 128;               // uint4 index, 256 per row
    const uint4 a = r0[c];
    const uint4 b = r1[c];
    float4 fa, fb;
    fa.x = bflo(a.x) + bflo(b.x); fa.y = bfhi(a.x) + bfhi(b.x);
    fa.z = bflo(a.y) + bflo(b.y); fa.w = bfhi(a.y) + bfhi(b.y);
    fb.x = bflo(a.z) + bflo(b.z); fb.y = bfhi(a.z) + bfhi(b.z);
    fb.z = bflo(a.w) + bflo(b.w); fb.w = bfhi(a.w) + bfhi(b.w);
    o[2 * c] = fa;
    o[2 * c + 1] = fb;
  }
}

// ================================= launch ==================================
extern "C" void kernel_launch(void* const* d_in, const int* in_sizes, int n_in,
                              void* d_out, int out_size, void* d_ws, size_t ws_size,
                              hipStream_t stream) {
  const float* x  = (const float*)d_in[0];
  const float* Wg = (const float*)d_in[1];
  const float* Wu = (const float*)d_in[2];
  const float* Wd = (const float*)d_in[3];
  const int*   sel = (const int*)d_in[4];
  const float* rw  = (const float*)d_in[5];
  float* out = (float*)d_out;

  char* base = (char*)d_ws;
  size_t off = 0;
  auto take = [&](size_t bytes) { char* p = base + off; off += bytes; return p; };
  unsigned short* xb     = (unsigned short*)take((size_t)T_TOK * H_DIM * 2);
  unsigned short* WguT   = (unsigned short*)take((size_t)E_NUM * 2048 * H_DIM * 2);
  unsigned short* WdT    = (unsigned short*)take((size_t)E_NUM * H_DIM * I_DIM * 2);
  unsigned short* a_pair = (unsigned short*)take((size_t)CAP * I_DIM * 2);
  unsigned short* d_pair = (unsigned short*)take((size_t)CAP * H_DIM * 2);
  int*   pair_token  = (int*)take(CAP * 4);
  float* pair_weight = (float*)take(CAP * 4);
  int*   inv         = (int*)take(NPAIR * 4);
  int*   tile_expert = (int*)take(512);
  int*   tile_pos    = (int*)take(512);
  (void)off;

  hipFuncSetAttribute((const void*)&moe_gemm<0>,
                      hipFuncAttributeMaxDynamicSharedMemorySize, 65536);
  hipFuncSetAttribute((const void*)&moe_gemm<1>,
                      hipFuncAttributeMaxDynamicSharedMemorySize, 65536);

  prep_all<<<PREP_BLKS, 512, 0, stream>>>(
      (const float4*)x, (ushort4*)xb, Wg, Wu, Wd, WguT, WdT, sel, rw,
      pair_token, pair_weight, inv, tile_expert, tile_pos);

  moe_gemm<0><<<NTB, 256, 65536, stream>>>(
      xb, WguT, pair_token, pair_weight, tile_expert, tile_pos,
      (unsigned int*)a_pair, nullptr);

  moe_gemm<1><<<NTB, 256, 65536, stream>>>(
      a_pair, WdT, pair_token, pair_weight, tile_expert, tile_pos,
      nullptr, d_pair);

  combine<<<T_TOK / 2, 256, 0, stream>>>(d_pair, inv, out);
}